// Round 21
// baseline (155.024 us; speedup 1.0000x reference)
//
#include <hip/hip_runtime.h>
#include <hip/hip_bf16.h>
#include <math.h>

#define NNODES 50000
#define FIN 256
#define HH 4
#define CC 32
#define D1 128   // H*C
#define CLS 16
#define NBUCK ((NNODES + 255) >> 8)   // 196 buckets of 256 nodes
#define CHUNK 4096
#define GEMMBLK ((NNODES + 63) / 64)  // 782
#define WPREPBLK ((FIN*D1 + 255) / 256) // 128

typedef __attribute__((ext_vector_type(8))) short bfrag8;   // 8 bf16 = 4 VGPRs
typedef __attribute__((ext_vector_type(4))) float facc4;

__device__ __forceinline__ float lrelu(float x){ return x > 0.f ? x : 0.2f*x; }

// fast exp: v_exp_f32 computes 2^x; scores here are bounded so no special cases.
__device__ __forceinline__ float fexp(float x){
#if __has_builtin(__builtin_amdgcn_exp2f)
  return __builtin_amdgcn_exp2f(x * 1.4426950408889634f);
#else
  return exp2f(x * 1.4426950408889634f);
#endif
}

__device__ __forceinline__ unsigned short f2bu(float x){
  __hip_bfloat16 h = __float2bfloat16(x);
  return *reinterpret_cast<unsigned short*>(&h);
}
__device__ __forceinline__ unsigned int pbf(float a, float b){
  return (unsigned int)f2bu(a) | ((unsigned int)f2bu(b) << 16);
}
__device__ __forceinline__ float2 bf2x(unsigned int u){
  float2 r;
  r.x = __uint_as_float(u << 16);
  r.y = __uint_as_float(u & 0xffff0000u);
  return r;
}

// ========== K1: bucket_count (blocks 0..nCnt-1) || wprep (blocks nCnt..) ==========
__global__ __launch_bounds__(256) void k_count_wprep(
    const int* __restrict__ dsts, int* __restrict__ bcnt, int E, int nCnt,
    const float* __restrict__ W, unsigned short* __restrict__ Wt) {
  if ((int)blockIdx.x < nCnt) {
    __shared__ int cnt[NBUCK];
    for (int t=threadIdx.x; t<NBUCK; t+=256) cnt[t]=0;
    __syncthreads();
    int base = blockIdx.x*CHUNK, lim = min(base+CHUNK, E);
    for (int e = base+threadIdx.x; e < lim; e += 256)
      atomicAdd(&cnt[dsts[e]>>8], 1);
    __syncthreads();
    for (int t=threadIdx.x; t<NBUCK; t+=256)
      if (cnt[t]) atomicAdd(&bcnt[t], cnt[t]);
  } else {
    int t = ((int)blockIdx.x - nCnt)*256 + threadIdx.x;
    if (t < FIN*D1) {
      int k = t >> 7, c = t & 127;
      Wt[c*FIN + k] = f2bu(W[t]);
    }
  }
}

// ========== K2: bin (blocks 0..nBin-1, in-block scan of bcnt) || gemm1 (rest) ==========
__global__ __launch_bounds__(256) void k_bin_gemm(
    const float* __restrict__ x, const unsigned int* __restrict__ Wt,
    const float* __restrict__ asrc, const float* __restrict__ adst,
    unsigned int* __restrict__ h1b, float* __restrict__ as1, float* __restrict__ ad1,
    const int* __restrict__ srcs, const int* __restrict__ dsts,
    const int* __restrict__ bcnt, int* __restrict__ gprog,
    unsigned int* __restrict__ binned, int E, int nBin) {
  __shared__ unsigned int Bs[128*256/2];    // 64 KB (gemm branch)
  __shared__ unsigned int As[64*64/2];      // 8 KB  (gemm branch)
  if ((int)blockIdx.x < nBin) {
    // ---- bin branch ----
    __shared__ int cnt[NBUCK];
    __shared__ int rbase[NBUCK];
    __shared__ int gsh[NBUCK];
    __shared__ int wsum[4], wbase[4];
    int t = threadIdx.x;
    int orig = (t < NBUCK) ? bcnt[t] : 0;
    int v = orig;
    int ln = t & 63, wv = t >> 6;
    #pragma unroll
    for (int off=1; off<64; off<<=1){ int u=__shfl_up(v,off,64); if(ln>=off) v+=u; }
    if (ln==63) wsum[wv]=v;
    __syncthreads();
    if (t==0){
      int s=0;
      for(int k=0;k<4;k++){ wbase[k]=s; s+=wsum[k]; }
    }
    __syncthreads();
    if (t < NBUCK) gsh[t] = wbase[wv] + v - orig;
    for (int q=t; q<NBUCK; q+=256) cnt[q]=0;
    __syncthreads();
    int base = blockIdx.x*CHUNK, lim = min(base+CHUNK, E);
    for (int e = base+t; e < lim; e += 256)
      atomicAdd(&cnt[dsts[e]>>8], 1);
    __syncthreads();
    for (int q=t; q<NBUCK; q+=256){
      rbase[q] = cnt[q] ? gsh[q] + atomicAdd(&gprog[q], cnt[q]) : 0;
      cnt[q] = 0;
    }
    __syncthreads();
    for (int e = base+t; e < lim; e += 256){
      int d = dsts[e], s = srcs[e];
      int b = d >> 8;
      int p = rbase[b] + atomicAdd(&cnt[b], 1);
      binned[p] = ((unsigned int)s << 8) | (unsigned int)(d & 255);
    }
    return;
  }
  // ---- gemm1 branch (round-12 proven body, fused alpha epilogue) ----
  int tid = threadIdx.x;
  int wv = tid >> 6, lane = tid & 63;
  int r0 = ((int)blockIdx.x - nBin) * 64;

  for (int it = 0; it < 16; it++) {
    int w16 = it*256 + tid;
    int c = w16 >> 5, k8 = w16 & 31;
    uint4 v = ((const uint4*)Wt)[w16];
    int byt = (c*512 + k8*16) ^ ((c&7)<<4);
    *(uint4*)((char*)Bs + byt) = v;
  }

  facc4 acc[8];
  #pragma unroll
  for (int t=0;t<8;t++) acc[t] = (facc4){0.f,0.f,0.f,0.f};

  int arow = tid >> 2, apart = tid & 3;
  int mrow = lane & 15, kb = lane >> 4;

  for (int stage = 0; stage < 4; stage++) {
    int gr = r0 + arow;
    const float* src = x + (size_t)gr*FIN + stage*64 + apart*16;
    float4 f0, f1, f2, f3;
    if (gr < NNODES) {
      f0 = *(const float4*)(src);
      f1 = *(const float4*)(src+4);
      f2 = *(const float4*)(src+8);
      f3 = *(const float4*)(src+12);
    } else {
      f0 = f1 = f2 = f3 = make_float4(0.f,0.f,0.f,0.f);
    }
    uint4 u0, u1;
    u0.x = pbf(f0.x,f0.y); u0.y = pbf(f0.z,f0.w);
    u0.z = pbf(f1.x,f1.y); u0.w = pbf(f1.z,f1.w);
    u1.x = pbf(f2.x,f2.y); u1.y = pbf(f2.z,f2.w);
    u1.z = pbf(f3.x,f3.y); u1.w = pbf(f3.z,f3.w);
    __syncthreads();
    int b0 = (arow*128 + apart*32) ^ ((arow&7)<<4);
    int b1 = (arow*128 + apart*32 + 16) ^ ((arow&7)<<4);
    *(uint4*)((char*)As + b0) = u0;
    *(uint4*)((char*)As + b1) = u1;
    __syncthreads();
    #pragma unroll
    for (int ks = 0; ks < 2; ks++) {
      int row = wv*16 + mrow;
      int abyt = (row*128 + ks*64 + kb*16) ^ ((row&7)<<4);
      bfrag8 afrag = *(bfrag8*)((char*)As + abyt);
      #pragma unroll
      for (int ct = 0; ct < 8; ct++) {
        int c = ct*16 + mrow;
        int bbyt = (c*512 + stage*128 + ks*64 + kb*16) ^ ((c&7)<<4);
        bfrag8 bfrag = *(bfrag8*)((char*)Bs + bbyt);
        acc[ct] = __builtin_amdgcn_mfma_f32_16x16x32_bf16(afrag, bfrag, acc[ct], 0, 0, 0);
      }
    }
  }
  int orow0 = r0 + wv*16 + (lane>>4)*4;
  int ocol = lane & 15;
  float asr[8], adr[8];
  #pragma unroll
  for (int ct=0; ct<8; ct++){
    asr[ct] = asrc[ct*16 + ocol];
    adr[ct] = adst[ct*16 + ocol];
  }
  #pragma unroll
  for (int r=0; r<4; r++) {
    int gr = orow0 + r;
    float sh[4], dh[4];
    #pragma unroll
    for (int h=0; h<4; h++){
      sh[h] = acc[2*h][r]*asr[2*h] + acc[2*h+1][r]*asr[2*h+1];
      dh[h] = acc[2*h][r]*adr[2*h] + acc[2*h+1][r]*adr[2*h+1];
    }
    #pragma unroll
    for (int off=1; off<16; off<<=1){
      #pragma unroll
      for (int h=0;h<4;h++){
        sh[h] += __shfl_xor(sh[h], off, 64);
        dh[h] += __shfl_xor(dh[h], off, 64);
      }
    }
    if (gr < NNODES) {
      if (ocol == 0) {
        *(float4*)(as1 + (size_t)gr*4) = make_float4(sh[0], sh[1], sh[2], sh[3]);
        *(float4*)(ad1 + (size_t)gr*4) = make_float4(dh[0], dh[1], dh[2], dh[3]);
      }
      #pragma unroll
      for (int ct=0; ct<4; ct++)
        h1b[(size_t)gr*64 + ct*16 + ocol] = pbf(acc[ct][r], acc[ct+4][r]);
    }
  }
}

// ---------------- Phase D: bucketcsr (in-block scan of bcnt for gstart) ----------------
__global__ __launch_bounds__(256) void bucketcsr_kernel(const int* __restrict__ bcnt,
                                                        const unsigned int* __restrict__ binned,
                                                        int* __restrict__ offs,
                                                        unsigned short* __restrict__ srcsort, int E) {
  int b = blockIdx.x;
  int t = threadIdx.x;
  __shared__ int gsh[NBUCK+1];
  __shared__ int cnt[256];
  __shared__ int cur[256];
  __shared__ int wsum[4], wbase[4];
  {
    int orig = (t < NBUCK) ? bcnt[t] : 0;
    int v = orig;
    int ln = t & 63, wv = t >> 6;
    #pragma unroll
    for (int off=1; off<64; off<<=1){ int u=__shfl_up(v,off,64); if(ln>=off) v+=u; }
    if (ln==63) wsum[wv]=v;
    __syncthreads();
    if (t==0){
      int s=0;
      for(int k=0;k<4;k++){ wbase[k]=s; s+=wsum[k]; }
      gsh[0]=0;
    }
    __syncthreads();
    if (t < NBUCK) gsh[t+1] = wbase[wv] + v;
  }
  cnt[t] = 0;
  __syncthreads();
  int s0 = gsh[b], s1 = gsh[b+1];
  for (int j = s0+t; j < s1; j += 256)
    atomicAdd(&cnt[binned[j] & 255], 1);
  __syncthreads();
  int orig = cnt[t], v = orig;
  int ln = t & 63, wv = t >> 6;
  #pragma unroll
  for (int off=1; off<64; off<<=1){ int u=__shfl_up(v,off,64); if(ln>=off) v+=u; }
  __syncthreads();
  if (ln==63) wsum[wv]=v;
  __syncthreads();
  if (t==0){
    int s=0;
    for(int k=0;k<4;k++){ wbase[k]=s; s+=wsum[k]; }
  }
  __syncthreads();
  int excl = wbase[wv] + v - orig;
  cur[t] = excl;
  int node = b*256 + t;
  if (node < NNODES) offs[node] = s0 + excl;
  if (node == NNODES-1) offs[NNODES] = E;
  __syncthreads();
  for (int j = s0+t; j < s1; j += 256){
    unsigned int e = binned[j];
    int p = s0 + atomicAdd(&cur[e & 255], 1);
    srcsort[p] = (unsigned short)(e >> 8);
  }
}

// ---------------- agg1 + fused layer-2 projection (MFMA epilogue, XOR-swizzled LDS) ----------------
// Round-20's MFMA epilogue had 14.8M bank conflicts: o1h/w2t rows are 256B
// apart, so fragment reads put all 16 m-lanes on one bank (the G4 D=128
// hazard). Fix = gemm1's XOR swizzle, byte ^= (row&7)<<4, on both write and
// read; w2t staging re-indexed so consecutive lanes write consecutive k.
__global__ __launch_bounds__(256) void agg1_proj_kernel(
    const unsigned int* __restrict__ h1b, const float* __restrict__ as1,
    const float* __restrict__ ad1, const int* __restrict__ offs,
    const unsigned short* __restrict__ srcsort, const float* __restrict__ b1,
    const float* __restrict__ W2, const float* __restrict__ asrc2,
    const float* __restrict__ adst2,
    __hip_bfloat16* __restrict__ h2b, float* __restrict__ as2, float* __restrict__ ad2) {
  __shared__ float exs[4][4][64];          // [warp][head][chunk-slot] 4 KB
  __shared__ int   ss [4][64];             // 1 KB
  __shared__ unsigned short w2t[CLS*D1];   // 4 KB: W2^T bf16, swizzled rows
  __shared__ unsigned short o1h[16*D1];    // 4 KB: out1 rows bf16, swizzled rows
  // stage W2^T (bf16), swizzled: element (c,k) at byte (c*256 + k*2) ^ ((c&7)<<4).
  // Loop indexed so consecutive lanes write consecutive k (no write conflicts).
  for (int l = threadIdx.x; l < D1*CLS; l += 256) {
    int c = l >> 7, k = l & 127;
    int byt = (c*256 + k*2) ^ ((c&7)<<4);
    *(unsigned short*)((char*)w2t + byt) = f2bu(W2[k*CLS + c]);
  }
  {
    unsigned int* oz = (unsigned int*)o1h;   // zero rows 4-15 (swizzle-invariant)
    oz[256 + threadIdx.x] = 0u;
    oz[512 + threadIdx.x] = 0u;
    oz[768 + threadIdx.x] = 0u;
  }
  __syncthreads();   // grid is exactly 50000/4 warps: no early-outs, barrier safe
  int warp = threadIdx.x >> 6;
  int lane = threadIdx.x & 63;
  int i = blockIdx.x * 4 + warp;
  int start = offs[i], end = offs[i+1];
  float4 adv = *(const float4*)(ad1 + (size_t)i*4);
  float4 asv = *(const float4*)(as1 + (size_t)i*4);
  float ad[4] = {adv.x, adv.y, adv.z, adv.w};
  float wself[4];
  {
    float av[4] = {asv.x, asv.y, asv.z, asv.w};
    #pragma unroll
    for (int h=0;h<4;h++) wself[h] = fexp(lrelu(av[h] + ad[h]));
  }
  int hlo = lane >> 5, hhi = hlo + 2;
  float den[4] = {0.f, 0.f, 0.f, 0.f};
  float accA, accB;
  {
    float2 hv = bf2x(h1b[(size_t)i*64 + lane]);
    accA = wself[hlo] * hv.x; accB = wself[hhi] * hv.y;
  }
  for (int c0 = start; c0 < end; c0 += 64) {
    int cnt = min(64, end - c0);
    int j = c0 + lane;
    if (j < end) {
      int s = (int)srcsort[j];
      float4 a = *(const float4*)(as1 + (size_t)s*4);
      float e0 = fexp(lrelu(a.x + ad[0]));
      float e1 = fexp(lrelu(a.y + ad[1]));
      float e2 = fexp(lrelu(a.z + ad[2]));
      float e3 = fexp(lrelu(a.w + ad[3]));
      den[0] += e0; den[1] += e1; den[2] += e2; den[3] += e3;
      exs[warp][0][lane] = e0; exs[warp][1][lane] = e1;
      exs[warp][2][lane] = e2; exs[warp][3][lane] = e3;
      ss[warp][lane] = s;
    }
    // 8 loads in flight hides the ~500cy L2/L3-miss latency (round-9/10 finding).
    #pragma unroll 8
    for (int j2 = 0; j2 < cnt; j2++) {
      int s = ss[warp][j2];
      float2 hv = bf2x(h1b[(size_t)s*64 + lane]);
      accA = fmaf(exs[warp][hlo][j2], hv.x, accA);
      accB = fmaf(exs[warp][hhi][j2], hv.y, accB);
    }
  }
  #pragma unroll
  for (int off=1; off<64; off<<=1) {
    #pragma unroll
    for (int h=0;h<4;h++) den[h] += __shfl_xor(den[h], off, 64);
  }
  float invlo = 1.f / (den[hlo] + wself[hlo] + 1e-16f);
  float invhi = 1.f / (den[hhi] + wself[hhi] + 1e-16f);
  float v0 = accA * invlo + b1[lane];
  float v1 = accB * invhi + b1[lane + 64];
  v0 = v0 > 0.f ? v0 : fexp(v0) - 1.f;   // ELU
  v1 = v1 > 0.f ? v1 : fexp(v1) - 1.f;
  // ---- pack out1 row to bf16 LDS (A row = warp), swizzled ----
  {
    int b0 = (warp*256 + lane*2)       ^ ((warp&7)<<4);
    int b1b = (warp*256 + 128 + lane*2) ^ ((warp&7)<<4);
    *(unsigned short*)((char*)o1h + b0)  = f2bu(v0);
    *(unsigned short*)((char*)o1h + b1b) = f2bu(v1);
  }
  __syncthreads();
  if (warp != 0) return;   // no further barriers: safe for warps 1-3 to retire
  // ---- warp 0: projection of 4 rows via 4 MFMAs (swizzled fragment reads) ----
  int m = lane & 15, kb = lane >> 4;
  facc4 pc = (facc4){0.f,0.f,0.f,0.f};
  #pragma unroll
  for (int ks = 0; ks < 4; ks++) {
    int abyt = (m*256 + ks*64 + kb*16) ^ ((m&7)<<4);
    bfrag8 af = *(bfrag8*)((char*)o1h + abyt);
    bfrag8 bf = *(bfrag8*)((char*)w2t + abyt);
    pc = __builtin_amdgcn_mfma_f32_16x16x32_bf16(af, bf, pc, 0, 0, 0);
  }
  // C layout: col=lane&15, row=(lane>>4)*4+r -> rows 0-3 (the 4 nodes) in lanes 0-15
  int i0 = blockIdx.x * 4;
  float a2 = asrc2[m], d2w = adst2[m];
  #pragma unroll
  for (int r = 0; r < 4; r++) {
    float cv = pc[r];
    if (lane < 16) h2b[(size_t)(i0+r)*CLS + m] = __float2bfloat16(cv);
    float sv = cv * a2, dv = cv * d2w;
    #pragma unroll
    for (int off=1; off<16; off<<=1) { sv += __shfl_xor(sv, off, 64); dv += __shfl_xor(dv, off, 64); }
    if (lane == 0) { as2[i0+r] = sv; ad2[i0+r] = dv; }
  }
}

// ---------------- layer-2 softmax + aggregation, single pass (round-12 version) ----------------
__global__ __launch_bounds__(256) void agg2_kernel(
    const unsigned int* __restrict__ h2b, const float* __restrict__ as2,
    const float* __restrict__ ad2, const int* __restrict__ offs,
    const unsigned short* __restrict__ srcsort, const float* __restrict__ b2,
    float* __restrict__ out) {
  int warp = threadIdx.x >> 6, lane = threadIdx.x & 63;
  int i = blockIdx.x*4 + warp;
  if (i >= NNODES) return;
  int start = offs[i], end = offs[i+1];
  float ad = ad2[i];
  float wself = fexp(lrelu(as2[i] + ad));
  int g = lane >> 3, cp = lane & 7;
  float2 acc = make_float2(0.f, 0.f);
  float denp = 0.f;
  if (g == 0) {
    float2 hv = bf2x(h2b[(size_t)i*(CLS/2) + cp]);
    acc.x = wself*hv.x; acc.y = wself*hv.y;
    denp = wself;
  }
  #pragma unroll 4
  for (int j = start + g; j < end; j += 8) {
    int s = (int)srcsort[j];
    float w = fexp(lrelu(as2[s] + ad));
    denp += w;
    float2 hv = bf2x(h2b[(size_t)s*(CLS/2) + cp]);
    acc.x = fmaf(w, hv.x, acc.x);
    acc.y = fmaf(w, hv.y, acc.y);
  }
  #pragma unroll
  for (int off=8; off<64; off<<=1) {
    acc.x += __shfl_xor(acc.x, off, 64);
    acc.y += __shfl_xor(acc.y, off, 64);
    denp  += __shfl_xor(denp,  off, 64);
  }
  if (lane < 8) {
    float inv = 1.f / (denp + 1e-16f);
    float2 o;
    o.x = acc.x * inv + b2[2*cp];
    o.y = acc.y * inv + b2[2*cp+1];
    *(float2*)(out + (size_t)i*CLS + 2*cp) = o;
  }
}

extern "C" void kernel_launch(void* const* d_in, const int* in_sizes, int n_in,
                              void* d_out, int out_size, void* d_ws, size_t ws_size,
                              hipStream_t stream) {
  const float* x     = (const float*)d_in[0];
  const int*   eidx  = (const int*)d_in[1];
  const float* W1    = (const float*)d_in[2];
  const float* asrc1 = (const float*)d_in[3];
  const float* adst1 = (const float*)d_in[4];
  const float* b1    = (const float*)d_in[5];
  const float* W2    = (const float*)d_in[6];
  const float* asrc2 = (const float*)d_in[7];
  const float* adst2 = (const float*)d_in[8];
  const float* b2    = (const float*)d_in[9];
  float* out = (float*)d_out;

  const int E = in_sizes[1] / 2;
  const int* srcs = eidx;
  const int* dsts = eidx + E;
  const int EBLK = (E + CHUNK - 1) / CHUNK;

  char* ws = (char*)d_ws;
  size_t off = 0;
  auto alloc = [&](size_t bytes) -> void* {
    void* p = ws + off;
    off = (off + bytes + 255) & ~(size_t)255;
    return p;
  };
  unsigned int*   h1b     = (unsigned int*)alloc((size_t)NNODES*(D1/2)*4);
  unsigned short* Wt      = (unsigned short*)alloc((size_t)FIN*D1*2);
  float*          as1     = (float*)alloc((size_t)NNODES*HH*4);
  float*          ad1     = (float*)alloc((size_t)NNODES*HH*4);
  __hip_bfloat16* h2b     = (__hip_bfloat16*)alloc((size_t)NNODES*CLS*2);
  float*          as2     = (float*)alloc((size_t)NNODES*4);
  float*          ad2     = (float*)alloc((size_t)NNODES*4);
  int*            bcnt    = (int*)alloc((size_t)NBUCK*2*4);   // bcnt | gprog (zeroed together)
  int*            gprog   = bcnt + NBUCK;
  int*            offs    = (int*)alloc((size_t)(NNODES+1)*4);
  unsigned int*   binned  = (unsigned int*)alloc((size_t)E*4);
  unsigned short* srcsort = (unsigned short*)alloc((size_t)E*2);

  (void)hipMemsetAsync(bcnt, 0, (size_t)NBUCK*2*4, stream);

  // K1: bucket histogram || W1 transpose+bf16 (independent)
  k_count_wprep<<<EBLK + WPREPBLK, 256, 0, stream>>>(dsts, bcnt, E, EBLK, W1, Wt);

  // K2: bin (in-block scan, blocks 0..EBLK-1) || GEMM1+alpha (rest)
  k_bin_gemm<<<EBLK + GEMMBLK, 256, 0, stream>>>(x, (const unsigned int*)Wt,
                                                 asrc1, adst1, h1b, as1, ad1,
                                                 srcs, dsts, bcnt, gprog,
                                                 binned, E, EBLK);

  // K3: per-bucket CSR finalize (in-block scan for gstart)
  bucketcsr_kernel<<<NBUCK, 256, 0, stream>>>(bcnt, binned, offs, srcsort, E);

  // K4: layer-1 attention + aggregation + bias + ELU + MFMA layer-2 projection
  agg1_proj_kernel<<<(NNODES+3)/4, 256, 0, stream>>>(h1b, as1, ad1, offs, srcsort, b1,
                                                     W2, asrc2, adst2, h2b, as2, ad2);

  // K5: layer-2 attention + aggregation
  agg2_kernel<<<(NNODES+3)/4, 256, 0, stream>>>((const unsigned int*)h2b, as2, ad2, offs, srcsort, b2, out);
}

// Round 22
// 134.983 us; speedup vs baseline: 1.1485x; 1.1485x over previous
//
#include <hip/hip_runtime.h>
#include <hip/hip_bf16.h>
#include <math.h>

#define NNODES 50000
#define FIN 256
#define HH 4
#define CC 32
#define D1 128   // H*C
#define CLS 16
#define NBUCK ((NNODES + 255) >> 8)   // 196 buckets of 256 nodes
#define CHUNK 4096
#define GEMMBLK ((NNODES + 63) / 64)  // 782
#define WPREPBLK ((FIN*D1 + 255) / 256) // 128

typedef __attribute__((ext_vector_type(8))) short bfrag8;   // 8 bf16 = 4 VGPRs
typedef __attribute__((ext_vector_type(4))) float facc4;

__device__ __forceinline__ float lrelu(float x){ return x > 0.f ? x : 0.2f*x; }

// fast exp: v_exp_f32 computes 2^x; scores here are bounded so no special cases.
__device__ __forceinline__ float fexp(float x){
#if __has_builtin(__builtin_amdgcn_exp2f)
  return __builtin_amdgcn_exp2f(x * 1.4426950408889634f);
#else
  return exp2f(x * 1.4426950408889634f);
#endif
}

__device__ __forceinline__ unsigned short f2bu(float x){
  __hip_bfloat16 h = __float2bfloat16(x);
  return *reinterpret_cast<unsigned short*>(&h);
}
__device__ __forceinline__ unsigned int pbf(float a, float b){
  return (unsigned int)f2bu(a) | ((unsigned int)f2bu(b) << 16);
}
__device__ __forceinline__ float2 bf2x(unsigned int u){
  float2 r;
  r.x = __uint_as_float(u << 16);
  r.y = __uint_as_float(u & 0xffff0000u);
  return r;
}

// ========== K1: bucket_count (blocks 0..nCnt-1) || wprep (blocks nCnt..) ==========
__global__ __launch_bounds__(256) void k_count_wprep(
    const int* __restrict__ dsts, int* __restrict__ bcnt, int E, int nCnt,
    const float* __restrict__ W, unsigned short* __restrict__ Wt) {
  if ((int)blockIdx.x < nCnt) {
    __shared__ int cnt[NBUCK];
    for (int t=threadIdx.x; t<NBUCK; t+=256) cnt[t]=0;
    __syncthreads();
    int base = blockIdx.x*CHUNK, lim = min(base+CHUNK, E);
    for (int e = base+threadIdx.x; e < lim; e += 256)
      atomicAdd(&cnt[dsts[e]>>8], 1);
    __syncthreads();
    for (int t=threadIdx.x; t<NBUCK; t+=256)
      if (cnt[t]) atomicAdd(&bcnt[t], cnt[t]);
  } else {
    int t = ((int)blockIdx.x - nCnt)*256 + threadIdx.x;
    if (t < FIN*D1) {
      int k = t >> 7, c = t & 127;
      Wt[c*FIN + k] = f2bu(W[t]);
    }
  }
}

// ========== K2: bin (blocks 0..nBin-1, in-block scan of bcnt) || gemm1 (rest) ==========
__global__ __launch_bounds__(256) void k_bin_gemm(
    const float* __restrict__ x, const unsigned int* __restrict__ Wt,
    const float* __restrict__ asrc, const float* __restrict__ adst,
    unsigned int* __restrict__ h1b, float* __restrict__ as1, float* __restrict__ ad1,
    const int* __restrict__ srcs, const int* __restrict__ dsts,
    const int* __restrict__ bcnt, int* __restrict__ gprog,
    unsigned int* __restrict__ binned, int E, int nBin) {
  __shared__ unsigned int Bs[128*256/2];    // 64 KB (gemm branch)
  __shared__ unsigned int As[64*64/2];      // 8 KB  (gemm branch)
  if ((int)blockIdx.x < nBin) {
    // ---- bin branch ----
    __shared__ int cnt[NBUCK];
    __shared__ int rbase[NBUCK];
    __shared__ int gsh[NBUCK];
    __shared__ int wsum[4], wbase[4];
    int t = threadIdx.x;
    int orig = (t < NBUCK) ? bcnt[t] : 0;
    int v = orig;
    int ln = t & 63, wv = t >> 6;
    #pragma unroll
    for (int off=1; off<64; off<<=1){ int u=__shfl_up(v,off,64); if(ln>=off) v+=u; }
    if (ln==63) wsum[wv]=v;
    __syncthreads();
    if (t==0){
      int s=0;
      for(int k=0;k<4;k++){ wbase[k]=s; s+=wsum[k]; }
    }
    __syncthreads();
    if (t < NBUCK) gsh[t] = wbase[wv] + v - orig;
    for (int q=t; q<NBUCK; q+=256) cnt[q]=0;
    __syncthreads();
    int base = blockIdx.x*CHUNK, lim = min(base+CHUNK, E);
    for (int e = base+t; e < lim; e += 256)
      atomicAdd(&cnt[dsts[e]>>8], 1);
    __syncthreads();
    for (int q=t; q<NBUCK; q+=256){
      rbase[q] = cnt[q] ? gsh[q] + atomicAdd(&gprog[q], cnt[q]) : 0;
      cnt[q] = 0;
    }
    __syncthreads();
    for (int e = base+t; e < lim; e += 256){
      int d = dsts[e], s = srcs[e];
      int b = d >> 8;
      int p = rbase[b] + atomicAdd(&cnt[b], 1);
      binned[p] = ((unsigned int)s << 8) | (unsigned int)(d & 255);
    }
    return;
  }
  // ---- gemm1 branch (round-12 proven body, fused alpha epilogue) ----
  int tid = threadIdx.x;
  int wv = tid >> 6, lane = tid & 63;
  int r0 = ((int)blockIdx.x - nBin) * 64;

  for (int it = 0; it < 16; it++) {
    int w16 = it*256 + tid;
    int c = w16 >> 5, k8 = w16 & 31;
    uint4 v = ((const uint4*)Wt)[w16];
    int byt = (c*512 + k8*16) ^ ((c&7)<<4);
    *(uint4*)((char*)Bs + byt) = v;
  }

  facc4 acc[8];
  #pragma unroll
  for (int t=0;t<8;t++) acc[t] = (facc4){0.f,0.f,0.f,0.f};

  int arow = tid >> 2, apart = tid & 3;
  int mrow = lane & 15, kb = lane >> 4;

  for (int stage = 0; stage < 4; stage++) {
    int gr = r0 + arow;
    const float* src = x + (size_t)gr*FIN + stage*64 + apart*16;
    float4 f0, f1, f2, f3;
    if (gr < NNODES) {
      f0 = *(const float4*)(src);
      f1 = *(const float4*)(src+4);
      f2 = *(const float4*)(src+8);
      f3 = *(const float4*)(src+12);
    } else {
      f0 = f1 = f2 = f3 = make_float4(0.f,0.f,0.f,0.f);
    }
    uint4 u0, u1;
    u0.x = pbf(f0.x,f0.y); u0.y = pbf(f0.z,f0.w);
    u0.z = pbf(f1.x,f1.y); u0.w = pbf(f1.z,f1.w);
    u1.x = pbf(f2.x,f2.y); u1.y = pbf(f2.z,f2.w);
    u1.z = pbf(f3.x,f3.y); u1.w = pbf(f3.z,f3.w);
    __syncthreads();
    int b0 = (arow*128 + apart*32) ^ ((arow&7)<<4);
    int b1 = (arow*128 + apart*32 + 16) ^ ((arow&7)<<4);
    *(uint4*)((char*)As + b0) = u0;
    *(uint4*)((char*)As + b1) = u1;
    __syncthreads();
    #pragma unroll
    for (int ks = 0; ks < 2; ks++) {
      int row = wv*16 + mrow;
      int abyt = (row*128 + ks*64 + kb*16) ^ ((row&7)<<4);
      bfrag8 afrag = *(bfrag8*)((char*)As + abyt);
      #pragma unroll
      for (int ct = 0; ct < 8; ct++) {
        int c = ct*16 + mrow;
        int bbyt = (c*512 + stage*128 + ks*64 + kb*16) ^ ((c&7)<<4);
        bfrag8 bfrag = *(bfrag8*)((char*)Bs + bbyt);
        acc[ct] = __builtin_amdgcn_mfma_f32_16x16x32_bf16(afrag, bfrag, acc[ct], 0, 0, 0);
      }
    }
  }
  int orow0 = r0 + wv*16 + (lane>>4)*4;
  int ocol = lane & 15;
  float asr[8], adr[8];
  #pragma unroll
  for (int ct=0; ct<8; ct++){
    asr[ct] = asrc[ct*16 + ocol];
    adr[ct] = adst[ct*16 + ocol];
  }
  #pragma unroll
  for (int r=0; r<4; r++) {
    int gr = orow0 + r;
    float sh[4], dh[4];
    #pragma unroll
    for (int h=0; h<4; h++){
      sh[h] = acc[2*h][r]*asr[2*h] + acc[2*h+1][r]*asr[2*h+1];
      dh[h] = acc[2*h][r]*adr[2*h] + acc[2*h+1][r]*adr[2*h+1];
    }
    #pragma unroll
    for (int off=1; off<16; off<<=1){
      #pragma unroll
      for (int h=0;h<4;h++){
        sh[h] += __shfl_xor(sh[h], off, 64);
        dh[h] += __shfl_xor(dh[h], off, 64);
      }
    }
    if (gr < NNODES) {
      if (ocol == 0) {
        *(float4*)(as1 + (size_t)gr*4) = make_float4(sh[0], sh[1], sh[2], sh[3]);
        *(float4*)(ad1 + (size_t)gr*4) = make_float4(dh[0], dh[1], dh[2], dh[3]);
      }
      #pragma unroll
      for (int ct=0; ct<4; ct++)
        h1b[(size_t)gr*64 + ct*16 + ocol] = pbf(acc[ct][r], acc[ct+4][r]);
    }
  }
}

// ---------------- Phase D: bucketcsr (in-block scan of bcnt for gstart) ----------------
__global__ __launch_bounds__(256) void bucketcsr_kernel(const int* __restrict__ bcnt,
                                                        const unsigned int* __restrict__ binned,
                                                        int* __restrict__ offs,
                                                        unsigned short* __restrict__ srcsort, int E) {
  int b = blockIdx.x;
  int t = threadIdx.x;
  __shared__ int gsh[NBUCK+1];
  __shared__ int cnt[256];
  __shared__ int cur[256];
  __shared__ int wsum[4], wbase[4];
  {
    int orig = (t < NBUCK) ? bcnt[t] : 0;
    int v = orig;
    int ln = t & 63, wv = t >> 6;
    #pragma unroll
    for (int off=1; off<64; off<<=1){ int u=__shfl_up(v,off,64); if(ln>=off) v+=u; }
    if (ln==63) wsum[wv]=v;
    __syncthreads();
    if (t==0){
      int s=0;
      for(int k=0;k<4;k++){ wbase[k]=s; s+=wsum[k]; }
      gsh[0]=0;
    }
    __syncthreads();
    if (t < NBUCK) gsh[t+1] = wbase[wv] + v;
  }
  cnt[t] = 0;
  __syncthreads();
  int s0 = gsh[b], s1 = gsh[b+1];
  for (int j = s0+t; j < s1; j += 256)
    atomicAdd(&cnt[binned[j] & 255], 1);
  __syncthreads();
  int orig = cnt[t], v = orig;
  int ln = t & 63, wv = t >> 6;
  #pragma unroll
  for (int off=1; off<64; off<<=1){ int u=__shfl_up(v,off,64); if(ln>=off) v+=u; }
  __syncthreads();
  if (ln==63) wsum[wv]=v;
  __syncthreads();
  if (t==0){
    int s=0;
    for(int k=0;k<4;k++){ wbase[k]=s; s+=wsum[k]; }
  }
  __syncthreads();
  int excl = wbase[wv] + v - orig;
  cur[t] = excl;
  int node = b*256 + t;
  if (node < NNODES) offs[node] = s0 + excl;
  if (node == NNODES-1) offs[NNODES] = E;
  __syncthreads();
  for (int j = s0+t; j < s1; j += 256){
    unsigned int e = binned[j];
    int p = s0 + atomicAdd(&cur[e & 255], 1);
    srcsort[p] = (unsigned short)(e >> 8);
  }
}

// ---------------- agg1 + fused layer-2 projection (round-19 champion) ----------------
// Per-warp GEMV epilogue, NO post-gather block barrier (MFMA epilogue variants
// R20/R21 regressed: barrier couples warps' degree-variance + staging issues).
// W2 row-interleaved: W2[k][c] at w_s[(k&31)*64 + (k>>5)*16 + c]; read addr
// kk*64 + lane -> 2-way conflicts only (free), base+immediate ds_read.
__global__ __launch_bounds__(256) void agg1_proj_kernel(
    const unsigned int* __restrict__ h1b, const float* __restrict__ as1,
    const float* __restrict__ ad1, const int* __restrict__ offs,
    const unsigned short* __restrict__ srcsort, const float* __restrict__ b1,
    const float* __restrict__ W2, const float* __restrict__ asrc2,
    const float* __restrict__ adst2,
    __hip_bfloat16* __restrict__ h2b, float* __restrict__ as2, float* __restrict__ ad2) {
  __shared__ float exs[4][4][64];   // [warp][head][chunk-slot]
  __shared__ int   ss [4][64];
  __shared__ float w_s[D1*CLS];     // 8 KB: W2, row-interleaved (kk major)
  __shared__ float o1[4][132];      // padded out1 row per warp (idx k+(k>>5))
  for (int l = threadIdx.x; l < D1*CLS; l += 256) {
    int k = l >> 4, c = l & 15;
    w_s[(k & 31)*64 + (k >> 5)*16 + c] = W2[l];
  }
  __syncthreads();   // grid is exactly 50000/4 warps: no early-outs, barrier safe
  int warp = threadIdx.x >> 6;
  int lane = threadIdx.x & 63;
  int i = blockIdx.x * 4 + warp;
  int start = offs[i], end = offs[i+1];
  float4 adv = *(const float4*)(ad1 + (size_t)i*4);
  float4 asv = *(const float4*)(as1 + (size_t)i*4);
  float ad[4] = {adv.x, adv.y, adv.z, adv.w};
  float wself[4];
  {
    float av[4] = {asv.x, asv.y, asv.z, asv.w};
    #pragma unroll
    for (int h=0;h<4;h++) wself[h] = fexp(lrelu(av[h] + ad[h]));
  }
  int hlo = lane >> 5, hhi = hlo + 2;
  float den[4] = {0.f, 0.f, 0.f, 0.f};
  float accA, accB;
  {
    float2 hv = bf2x(h1b[(size_t)i*64 + lane]);
    accA = wself[hlo] * hv.x; accB = wself[hhi] * hv.y;
  }
  for (int c0 = start; c0 < end; c0 += 64) {
    int cnt = min(64, end - c0);
    int j = c0 + lane;
    if (j < end) {
      int s = (int)srcsort[j];
      float4 a = *(const float4*)(as1 + (size_t)s*4);
      float e0 = fexp(lrelu(a.x + ad[0]));
      float e1 = fexp(lrelu(a.y + ad[1]));
      float e2 = fexp(lrelu(a.z + ad[2]));
      float e3 = fexp(lrelu(a.w + ad[3]));
      den[0] += e0; den[1] += e1; den[2] += e2; den[3] += e3;
      exs[warp][0][lane] = e0; exs[warp][1][lane] = e1;
      exs[warp][2][lane] = e2; exs[warp][3][lane] = e3;
      ss[warp][lane] = s;
    }
    // 8 loads in flight hides the ~500cy L2/L3-miss latency (round-9/10 finding).
    #pragma unroll 8
    for (int j2 = 0; j2 < cnt; j2++) {
      int s = ss[warp][j2];
      float2 hv = bf2x(h1b[(size_t)s*64 + lane]);
      accA = fmaf(exs[warp][hlo][j2], hv.x, accA);
      accB = fmaf(exs[warp][hhi][j2], hv.y, accB);
    }
  }
  #pragma unroll
  for (int off=1; off<64; off<<=1) {
    #pragma unroll
    for (int h=0;h<4;h++) den[h] += __shfl_xor(den[h], off, 64);
  }
  float invlo = 1.f / (den[hlo] + wself[hlo] + 1e-16f);
  float invhi = 1.f / (den[hhi] + wself[hhi] + 1e-16f);
  float v0 = accA * invlo + b1[lane];
  float v1 = accB * invhi + b1[lane + 64];
  v0 = v0 > 0.f ? v0 : fexp(v0) - 1.f;   // ELU
  v1 = v1 > 0.f ? v1 : fexp(v1) - 1.f;
  // ---- fused projection: out1 row -> LDS (padded), warp-local GEMV ----
  o1[warp][lane + (lane>>5)] = v0;
  {
    int k2 = lane + 64;
    o1[warp][k2 + (k2>>5)] = v1;
  }
  int c = lane & 15, kq = lane >> 4;
  float acc2 = 0.f;
  #pragma unroll
  for (int kk=0; kk<32; kk++) {
    int k = kq*32 + kk;
    acc2 = fmaf(o1[warp][k + (k>>5)], w_s[kk*64 + lane], acc2);
  }
  acc2 += __shfl_xor(acc2, 16, 64);
  acc2 += __shfl_xor(acc2, 32, 64);
  if (lane < 16) h2b[(size_t)i*CLS + c] = __float2bfloat16(acc2);
  float s2 = acc2 * asrc2[c];
  float d2 = acc2 * adst2[c];
  #pragma unroll
  for (int off=1; off<16; off<<=1) { s2 += __shfl_xor(s2, off, 64); d2 += __shfl_xor(d2, off, 64); }
  if (lane == 0) { as2[i] = s2; ad2[i] = d2; }
}

// ---------------- layer-2 softmax + aggregation, single pass (round-12 version) ----------------
__global__ __launch_bounds__(256) void agg2_kernel(
    const unsigned int* __restrict__ h2b, const float* __restrict__ as2,
    const float* __restrict__ ad2, const int* __restrict__ offs,
    const unsigned short* __restrict__ srcsort, const float* __restrict__ b2,
    float* __restrict__ out) {
  int warp = threadIdx.x >> 6, lane = threadIdx.x & 63;
  int i = blockIdx.x*4 + warp;
  if (i >= NNODES) return;
  int start = offs[i], end = offs[i+1];
  float ad = ad2[i];
  float wself = fexp(lrelu(as2[i] + ad));
  int g = lane >> 3, cp = lane & 7;
  float2 acc = make_float2(0.f, 0.f);
  float denp = 0.f;
  if (g == 0) {
    float2 hv = bf2x(h2b[(size_t)i*(CLS/2) + cp]);
    acc.x = wself*hv.x; acc.y = wself*hv.y;
    denp = wself;
  }
  #pragma unroll 4
  for (int j = start + g; j < end; j += 8) {
    int s = (int)srcsort[j];
    float w = fexp(lrelu(as2[s] + ad));
    denp += w;
    float2 hv = bf2x(h2b[(size_t)s*(CLS/2) + cp]);
    acc.x = fmaf(w, hv.x, acc.x);
    acc.y = fmaf(w, hv.y, acc.y);
  }
  #pragma unroll
  for (int off=8; off<64; off<<=1) {
    acc.x += __shfl_xor(acc.x, off, 64);
    acc.y += __shfl_xor(acc.y, off, 64);
    denp  += __shfl_xor(denp,  off, 64);
  }
  if (lane < 8) {
    float inv = 1.f / (denp + 1e-16f);
    float2 o;
    o.x = acc.x * inv + b2[2*cp];
    o.y = acc.y * inv + b2[2*cp+1];
    *(float2*)(out + (size_t)i*CLS + 2*cp) = o;
  }
}

extern "C" void kernel_launch(void* const* d_in, const int* in_sizes, int n_in,
                              void* d_out, int out_size, void* d_ws, size_t ws_size,
                              hipStream_t stream) {
  const float* x     = (const float*)d_in[0];
  const int*   eidx  = (const int*)d_in[1];
  const float* W1    = (const float*)d_in[2];
  const float* asrc1 = (const float*)d_in[3];
  const float* adst1 = (const float*)d_in[4];
  const float* b1    = (const float*)d_in[5];
  const float* W2    = (const float*)d_in[6];
  const float* asrc2 = (const float*)d_in[7];
  const float* adst2 = (const float*)d_in[8];
  const float* b2    = (const float*)d_in[9];
  float* out = (float*)d_out;

  const int E = in_sizes[1] / 2;
  const int* srcs = eidx;
  const int* dsts = eidx + E;
  const int EBLK = (E + CHUNK - 1) / CHUNK;

  char* ws = (char*)d_ws;
  size_t off = 0;
  auto alloc = [&](size_t bytes) -> void* {
    void* p = ws + off;
    off = (off + bytes + 255) & ~(size_t)255;
    return p;
  };
  unsigned int*   h1b     = (unsigned int*)alloc((size_t)NNODES*(D1/2)*4);
  unsigned short* Wt      = (unsigned short*)alloc((size_t)FIN*D1*2);
  float*          as1     = (float*)alloc((size_t)NNODES*HH*4);
  float*          ad1     = (float*)alloc((size_t)NNODES*HH*4);
  __hip_bfloat16* h2b     = (__hip_bfloat16*)alloc((size_t)NNODES*CLS*2);
  float*          as2     = (float*)alloc((size_t)NNODES*4);
  float*          ad2     = (float*)alloc((size_t)NNODES*4);
  int*            bcnt    = (int*)alloc((size_t)NBUCK*2*4);   // bcnt | gprog (zeroed together)
  int*            gprog   = bcnt + NBUCK;
  int*            offs    = (int*)alloc((size_t)(NNODES+1)*4);
  unsigned int*   binned  = (unsigned int*)alloc((size_t)E*4);
  unsigned short* srcsort = (unsigned short*)alloc((size_t)E*2);

  (void)hipMemsetAsync(bcnt, 0, (size_t)NBUCK*2*4, stream);

  // K1: bucket histogram || W1 transpose+bf16 (independent)
  k_count_wprep<<<EBLK + WPREPBLK, 256, 0, stream>>>(dsts, bcnt, E, EBLK, W1, Wt);

  // K2: bin (in-block scan, blocks 0..EBLK-1) || GEMM1+alpha (rest)
  k_bin_gemm<<<EBLK + GEMMBLK, 256, 0, stream>>>(x, (const unsigned int*)Wt,
                                                 asrc1, adst1, h1b, as1, ad1,
                                                 srcs, dsts, bcnt, gprog,
                                                 binned, E, EBLK);

  // K3: per-bucket CSR finalize (in-block scan for gstart)
  bucketcsr_kernel<<<NBUCK, 256, 0, stream>>>(bcnt, binned, offs, srcsort, E);

  // K4: layer-1 attention + aggregation + bias + ELU + fused layer-2 projection
  agg1_proj_kernel<<<(NNODES+3)/4, 256, 0, stream>>>(h1b, as1, ad1, offs, srcsort, b1,
                                                     W2, asrc2, adst2, h2b, as2, ad2);

  // K5: layer-2 attention + aggregation
  agg2_kernel<<<(NNODES+3)/4, 256, 0, stream>>>((const unsigned int*)h2b, as2, ad2, offs, srcsort, b2, out);
}